// Round 1
// 135.442 us; speedup vs baseline: 1.0854x; 1.0854x over previous
//
#include <hip/hip_runtime.h>

// Problem constants
#define Bn  4
#define Cc  64      // channels
#define ICc 32      // inner channels
#define Hh  128
#define Ww  128
#define Nn  (Hh*Ww)     // 16384
#define Hp  (Hh/2)      // 64 pooled rows
#define Wp  (Ww/2)      // 64 pooled cols
#define PAD 66          // LDS tile row stride (floats)

// ws layout (floats):
//   [0, 4096)      A[b][i][j]  gram accumulator (zeroed here; ws is poisoned 0xAA)
//   [4096, 12288)  wT[img][c][ic]  transposed conv weights (img0=phi, img1=g)

// ---------------------------------------------------------------------------
// Kernel 0: zero gram + transpose weights into ws. 32 blocks x 256.
// ---------------------------------------------------------------------------
__global__ __launch_bounds__(256) void init_ws(
    const float* __restrict__ phi_w, const float* __restrict__ g_w,
    float* __restrict__ ws)
{
    const int gid = blockIdx.x * 256 + threadIdx.x;   // 0..8191
    if (gid < 4096) {
        ws[gid] = 0.f;                                 // A := 0
    } else {
        const int idx = gid - 4096;                    // 0..4095
        const int img = idx >> 11;                     // 0: phi, 1: g
        const int rem = idx & 2047;
        const int c = rem >> 5, i = rem & 31;          // wT[img][c][i] = w[i][c]
        ws[gid] = (img ? g_w : phi_w)[i * Cc + c];
    }
}

// ---------------------------------------------------------------------------
// Kernel 1: fused conv1x1 + 2x2 maxpool + partial gram.
// grid (Hp, B) = 256 blocks, block 512 (8 waves, 2/SIMD).
// Wave-uniform decomposition: pw = tid&63 (lane), icg = ((tid>>6)&3)*8,
// img = tid>>8 — icg/img forced to SGPR so weight fetches are SCALAR loads
// from the transposed copy in ws (zero LDS reads in phase A, no shfl).
// Each thread owns a full 2x2 pool window: 2 coalesced float2 loads per c,
// 32 FMAs per c into 8 IC x 4 px accumulators.
// Phase B: 512 threads, each does two (i,j) gram entries over 64 pooled cols.
// ---------------------------------------------------------------------------
__global__ __launch_bounds__(512) void conv_gram_kernel(
    const float* __restrict__ ref, const float* __restrict__ ref_align,
    const float* __restrict__ phi_b, const float* __restrict__ g_b,
    const float* __restrict__ wT,    // ws + 4096 (disjoint from A -> restrict ok)
    float* __restrict__ A)           // ws + 0
{
    __shared__ float tile[2][ICc][PAD];      // [img][ic][pw]

    const int b = blockIdx.y, ph = blockIdx.x, tid = threadIdx.x;
    const int pw  = tid & 63;                                          // lane id
    const int icg = __builtin_amdgcn_readfirstlane(((tid >> 6) & 3) * 8);
    const int img = __builtin_amdgcn_readfirstlane(tid >> 8);

    const float* in = img ? ref_align : ref;
    const float2* xrow0 = (const float2*)in + ((size_t)(b * Cc * Hh) + 2 * ph)     * (Ww / 2);
    const float2* xrow1 = (const float2*)in + ((size_t)(b * Cc * Hh) + 2 * ph + 1) * (Ww / 2);
    const int cs2 = (Hh * Ww) / 2;           // channel stride in float2
    const float* wt   = wT + img * (Cc * ICc) + icg;   // + c*ICc walks rows
    const float* bias = (img ? g_b : phi_b) + icg;

    float a00[8], a01[8], a10[8], a11[8];
    #pragma unroll
    for (int i = 0; i < 8; ++i) { a00[i] = a01[i] = a10[i] = a11[i] = 0.f; }

    #pragma unroll 8
    for (int c = 0; c < Cc; ++c) {
        const float2 v0 = xrow0[c * cs2 + pw];         // row 2ph,   cols 2pw..2pw+1
        const float2 v1 = xrow1[c * cs2 + pw];         // row 2ph+1
        const float* wr = wt + c * ICc;                // wave-uniform -> s_load
        #pragma unroll
        for (int i = 0; i < 8; ++i) {
            const float w = wr[i];
            a00[i] = fmaf(w, v0.x, a00[i]);
            a01[i] = fmaf(w, v0.y, a01[i]);
            a10[i] = fmaf(w, v1.x, a10[i]);
            a11[i] = fmaf(w, v1.y, a11[i]);
        }
    }

    #pragma unroll
    for (int i = 0; i < 8; ++i) {
        // bias is constant across the 2x2 window -> add after the max
        const float mx = fmaxf(fmaxf(a00[i], a01[i]), fmaxf(a10[i], a11[i]));
        tile[img][icg + i][pw] = mx + bias[i];
    }
    __syncthreads();

    // ---- Phase B: partial gram, two (i,j) per thread ----
    {
        const int j  = tid & 31;
        const int i0 = tid >> 5;                 // 0..15
        float s0 = 0.f, s1 = 0.f;
        #pragma unroll 8
        for (int p = 0; p < Wp / 2; ++p) {
            const float2 pv = *(const float2*)&tile[0][j][2 * p];        // 2-way alias: free
            const float2 g0 = *(const float2*)&tile[1][i0][2 * p];       // broadcast
            const float2 g1 = *(const float2*)&tile[1][i0 + 16][2 * p];  // broadcast
            s0 = fmaf(g0.x, pv.x, fmaf(g0.y, pv.y, s0));
            s1 = fmaf(g1.x, pv.x, fmaf(g1.y, pv.y, s1));
        }
        atomicAdd(A + ((size_t)b * ICc + i0)      * ICc + j, s0);
        atomicAdd(A + ((size_t)b * ICc + i0 + 16) * ICc + j, s1);
    }
}

// ---------------------------------------------------------------------------
// Kernel 2: fused combine + apply. o-split 8, float4 over n, float4 sM reads.
// grid 512 blocks x 256 (1-D, swizzled so the 8 oz-siblings sharing an
// x-chunk land on the same XCD for L2 reuse). Inner loop per 4 channels:
// 4 global b128 + 8 LDS b128 broadcasts + 128 FMA -> VALU-bound 2:1.
// ---------------------------------------------------------------------------
__global__ __launch_bounds__(256) void apply_kernel(
    const float* __restrict__ x, const float* __restrict__ A,
    const float* __restrict__ theta_w, const float* __restrict__ theta_b,
    const float* __restrict__ W_w,     const float* __restrict__ W_b,
    float* __restrict__ out)
{
    // id -> (nx, b, oz): xcd = id&7; siblings s=0..7 are 8 consecutive id/8
    // slots with identical id&7 -> same XCD under round-robin dispatch.
    const int id  = blockIdx.x;          // 0..511
    const int xcd = id & 7;
    const int t   = id >> 3;
    const int s   = t & 7;               // oz sibling 0..7
    const int ghi = t >> 3;              // 0..7
    const int g   = ghi * 8 + xcd;       // group 0..63 = (nx, b)
    const int nx  = g & 15;
    const int b   = g >> 4;
    const int ob  = s * 8;

    __shared__ __align__(16) float sA[ICc * ICc];
    __shared__ __align__(16) float sT[8 * ICc];
    __shared__ __align__(16) float sM[8 * Cc];
    __shared__ float sv[8];

    for (int idx = threadIdx.x; idx < ICc * ICc; idx += 256)
        sA[idx] = A[(size_t)b * ICc * ICc + idx];
    __syncthreads();

    {   // sT[ol][j] = (W_w[ob+ol,:] @ A)[j],  8*32 = 256 = blockDim
        const int ol = threadIdx.x >> 5, j = threadIdx.x & 31;
        const float* wr = W_w + (ob + ol) * ICc;
        float tacc = 0.f;
        #pragma unroll
        for (int i = 0; i < ICc; ++i) tacc = fmaf(wr[i], sA[i * ICc + j], tacc);
        sT[ol * ICc + j] = tacc;
    }
    __syncthreads();

    const float invN = 1.f / (float)Nn;
    for (int idx = threadIdx.x; idx < 8 * Cc; idx += 256) {
        const int ol = idx >> 6, c = idx & 63;
        float sacc = 0.f;
        #pragma unroll
        for (int j = 0; j < ICc; ++j) sacc = fmaf(sT[ol * ICc + j], theta_w[j * Cc + c], sacc);
        sM[idx] = sacc * invN + ((ob + ol) == c ? 1.f : 0.f);
    }
    if (threadIdx.x < 8) {
        float v = 0.f;
        #pragma unroll
        for (int j = 0; j < ICc; ++j) v = fmaf(sT[threadIdx.x * ICc + j], theta_b[j], v);
        sv[threadIdx.x] = v * invN + W_b[ob + threadIdx.x];
    }
    __syncthreads();

    const int n4 = nx * 256 + threadIdx.x;             // float4 index, 0..4095
    const float4* xb  = (const float4*)(x   + (size_t)b * Cc * Nn);
    float4*       ov4 = (float4*)      (out + (size_t)b * Cc * Nn);

    float4 acc[8];
    #pragma unroll
    for (int i = 0; i < 8; ++i) acc[i] = make_float4(sv[i], sv[i], sv[i], sv[i]);

#define FMA4(a, wv, xv) { (a).x = fmaf((wv), (xv).x, (a).x); \
                          (a).y = fmaf((wv), (xv).y, (a).y); \
                          (a).z = fmaf((wv), (xv).z, (a).z); \
                          (a).w = fmaf((wv), (xv).w, (a).w); }

    #pragma unroll 2
    for (int c4 = 0; c4 < Cc / 4; ++c4) {
        float4 xv0 = xb[(c4 * 4 + 0) * (Nn / 4) + n4];
        float4 xv1 = xb[(c4 * 4 + 1) * (Nn / 4) + n4];
        float4 xv2 = xb[(c4 * 4 + 2) * (Nn / 4) + n4];
        float4 xv3 = xb[(c4 * 4 + 3) * (Nn / 4) + n4];
        #pragma unroll
        for (int i = 0; i < 8; ++i) {
            const float4 w = *(const float4*)&sM[i * Cc + c4 * 4];  // b128 broadcast
            FMA4(acc[i], w.x, xv0);
            FMA4(acc[i], w.y, xv1);
            FMA4(acc[i], w.z, xv2);
            FMA4(acc[i], w.w, xv3);
        }
    }
#undef FMA4

    #pragma unroll
    for (int i = 0; i < 8; ++i)
        ov4[(size_t)(ob + i) * (Nn / 4) + n4] = acc[i];
}

// ---------------------------------------------------------------------------
extern "C" void kernel_launch(void* const* d_in, const int* in_sizes, int n_in,
                              void* d_out, int out_size, void* d_ws, size_t ws_size,
                              hipStream_t stream) {
    const float* target    = (const float*)d_in[0];
    const float* ref       = (const float*)d_in[1];
    const float* ref_align = (const float*)d_in[2];
    const float* theta_w   = (const float*)d_in[3];
    const float* theta_b   = (const float*)d_in[4];
    const float* phi_w     = (const float*)d_in[5];
    const float* phi_b     = (const float*)d_in[6];
    const float* g_w       = (const float*)d_in[7];
    const float* g_b       = (const float*)d_in[8];
    const float* W_w       = (const float*)d_in[9];
    const float* W_b       = (const float*)d_in[10];
    float* out = (float*)d_out;

    float* ws = (float*)d_ws;
    float* A  = ws;           // 16 KB gram
    float* wT = ws + 4096;    // 16 KB transposed conv weights

    init_ws<<<32, 256, 0, stream>>>(phi_w, g_w, ws);
    conv_gram_kernel<<<dim3(Hp, Bn), 512, 0, stream>>>(ref, ref_align,
                                                       phi_b, g_b, wT, A);
    apply_kernel<<<512, 256, 0, stream>>>(target, A, theta_w, theta_b,
                                          W_w, W_b, out);
}